// Round 11
// baseline (771.918 us; speedup 1.0000x reference)
//
#include <hip/hip_runtime.h>
#include <math.h>

#define NBATCH 8
#define NPTS   2048
#define NPOINT 512
#define KNB    16
#define NROWS  (NBATCH*NPOINT*KNB)   // 65536

typedef unsigned short ushort_t;
typedef unsigned int   uint_t;
typedef unsigned long long ull_t;
typedef __attribute__((ext_vector_type(8))) short  short8;   // 8 bf16 (4 VGPRs)
typedef __attribute__((ext_vector_type(4))) float  f32x4;    // MFMA C/D

// bankT element offsets (bf16, layout [n][k], k = m*CIN+c)
#define B0_OFF 0        // n=64,  K=512  -> 32768
#define B1_OFF 32768    // n=128, K=512  -> 65536
#define B2_OFF 98304    // n=256, K=1024 -> 262144
#define BT_TOT 360448

// ---------------------------------------------------------------------------
// Scratch in static __device__ globals. Referenced ONLY in device code.
// ---------------------------------------------------------------------------
__device__ __align__(16) int      g_fidx[NBATCH * NPOINT];        //  16 KB
__device__ __align__(16) int      g_knn [NROWS];                  // 256 KB
__device__ __align__(16) float    g_sums[1024];                   //   4 KB
__device__ __align__(16) float    g_pT  [NBATCH * NPTS * 64];     //   4 MB
__device__ __align__(16) float    g_S   [(size_t)3 * NROWS * 8];  //   6 MB
__device__ __align__(16) float    g_act1[(size_t)NROWS * 64];     //  16 MB
__device__ __align__(16) float    g_act2[(size_t)NROWS * 128];    //  32 MB
__device__ __align__(16) ushort_t g_bankT[BT_TOT];                // 704 KB bf16 [n][k]

// f32 -> bf16 round-to-nearest-even (finite inputs).
__device__ __forceinline__ ushort_t f2bf(float f) {
    uint_t u = __float_as_uint(f);
    return (ushort_t)((u + 0x7FFFu + ((u >> 16) & 1u)) >> 16);
}

// DPP-shifted copy of a u64 key (bound_ctrl=1: invalid lanes read 0, the
// identity for unsigned max of our non-negative keys).
template<int CTRL>
__device__ __forceinline__ ull_t dpp_u64(ull_t k) {
    int lo = (int)(uint_t)k;
    int hi = (int)(uint_t)(k >> 32);
    int slo = __builtin_amdgcn_update_dpp(0, lo, CTRL, 0xF, 0xF, true);
    int shi = __builtin_amdgcn_update_dpp(0, hi, CTRL, 0xF, 0xF, true);
    return ((ull_t)(uint_t)shi << 32) | (uint_t)slo;
}

// ---------------------------------------------------------------------------
// front_kernel: blocks 0-7 = FPS; 8-263 = transpose points; 264 = zero sums;
// 265-1672 = convert+transpose banks to bf16 [n][k] (hidden under FPS).
// FPS: DPP wave argmax (row_shr 1/2/4/8 + row_bcast 15/31 -> lane 63),
// packed key (f32bits(dist)<<32)|~idx, parity-buffered s_key, 1 barrier/iter.
// ---------------------------------------------------------------------------
__global__ __launch_bounds__(256) void front_kernel(const float* __restrict__ xyz,
                                                    const float* __restrict__ points,
                                                    const float* __restrict__ bank0,
                                                    const float* __restrict__ bank1,
                                                    const float* __restrict__ bank2) {
    __shared__ float smem[3 * NPTS + 16];
    const int bid = blockIdx.x;
    const int t = threadIdx.x;

    if (bid >= NBATCH) {
        if (bid < NBATCH + 256) {
            // ---- transpose points ----
            float (*tile)[65] = reinterpret_cast<float(*)[65]>(smem);
            const int blk = bid - NBATCH;
            const int b = blk >> 5;
            const int n0 = (blk & 31) * 64;
            const int lane = t & 63, q = t >> 6;
            #pragma unroll
            for (int i = 0; i < 16; ++i) {
                int c = q * 16 + i;
                tile[c][lane] = points[(b * 64 + c) * NPTS + n0 + lane];
            }
            __syncthreads();
            #pragma unroll
            for (int i = 0; i < 16; ++i) {
                int n = q * 16 + i;
                g_pT[(size_t)(b * NPTS + n0 + n) * 64 + lane] = tile[lane][n];
            }
        } else if (bid == NBATCH + 256) {
            // ---- zero BN-stats ----
            #pragma unroll
            for (int j = 0; j < 4; ++j) g_sums[j * 256 + t] = 0.0f;
        } else {
            // ---- bank convert+transpose: bankT[n*K+k] = bf16(bank[k*N+n]) ----
            const int e = (bid - (NBATCH + 257)) * 256 + t;
            if (e < 32768) {
                const int n = e >> 9, k = e & 511;
                g_bankT[B0_OFF + e] = f2bf(bank0[k * 64 + n]);
            } else if (e < 98304) {
                const int e1 = e - 32768;
                const int n = e1 >> 9, k = e1 & 511;
                g_bankT[B1_OFF + e1] = f2bf(bank1[k * 128 + n]);
            } else {
                const int e2 = e - 98304;
                const int n = e2 >> 10, k = e2 & 1023;
                g_bankT[B2_OFF + e2] = f2bf(bank2[k * 256 + n]);
            }
        }
        return;
    }

    // ---- FPS ----
    {
        #pragma clang fp contract(off)
        const int b = bid;
        const int lane = t & 63, w4 = t >> 6;
        const float* xb = xyz + b * 3 * NPTS;
        float* s_x = smem;
        float* s_y = smem + NPTS;
        float* s_z = smem + 2 * NPTS;
        ull_t* s_key = reinterpret_cast<ull_t*>(smem + 3 * NPTS);  // 8 slots
        float x[8], y[8], z[8], d[8];
        #pragma unroll
        for (int j = 0; j < 8; ++j) {
            int p = j * 256 + t;
            float vx = xb[p], vy = xb[NPTS + p], vz = xb[2*NPTS + p];
            x[j] = vx; y[j] = vy; z[j] = vz;
            s_x[p] = vx; s_y[p] = vy; s_z[p] = vz;
            d[j] = 1e10f;
        }
        __syncthreads();
        int far = 0;
        for (int i = 0; i < NPOINT; ++i) {
            if (t == 0) g_fidx[b * NPOINT + i] = far;
            float cx = s_x[far], cy = s_y[far], cz = s_z[far];
            float best = -1.0f; int bi = 0;
            #pragma unroll
            for (int j = 0; j < 8; ++j) {
                float dx = x[j] - cx;
                float dy = y[j] - cy;
                float dz = z[j] - cz;
                float dd = dx*dx + dy*dy;   // ((dx^2+dy^2)+dz^2) like np
                dd = dd + dz*dz;
                float dn = fminf(d[j], dd);
                d[j] = dn;
                if (dn > best) { best = dn; bi = j * 256 + t; }  // strict >
            }
            ull_t key = (((ull_t)__float_as_uint(best)) << 32) | (uint_t)(~bi);
            { ull_t s = dpp_u64<0x111>(key); if (s > key) key = s; }  // row_shr:1
            { ull_t s = dpp_u64<0x112>(key); if (s > key) key = s; }  // row_shr:2
            { ull_t s = dpp_u64<0x114>(key); if (s > key) key = s; }  // row_shr:4
            { ull_t s = dpp_u64<0x118>(key); if (s > key) key = s; }  // row_shr:8
            { ull_t s = dpp_u64<0x142>(key); if (s > key) key = s; }  // row_bcast:15
            { ull_t s = dpp_u64<0x143>(key); if (s > key) key = s; }  // row_bcast:31
            uint_t wlo = (uint_t)__builtin_amdgcn_readlane((int)(uint_t)key, 63);
            uint_t whi = (uint_t)__builtin_amdgcn_readlane((int)(uint_t)(key >> 32), 63);
            if (lane == 0) s_key[((i & 1) << 2) + w4] = ((ull_t)whi << 32) | wlo;
            __syncthreads();
            const ull_t* kb = s_key + ((i & 1) << 2);
            ull_t k0 = kb[0], k1 = kb[1], k2 = kb[2], k3 = kb[3];
            if (k1 > k0) k0 = k1;
            if (k3 > k2) k2 = k3;
            if (k2 > k0) k0 = k2;
            far = (int)(~(uint_t)k0) & (NPTS - 1);
        }
    }
}

// ---------------------------------------------------------------------------
// KNN: one wave per query. Expanded |a|^2+|b|^2-2ab form (contract off);
// 16 rounds of wave-min with index tie-break.
// ---------------------------------------------------------------------------
__global__ __launch_bounds__(256) void knn_kernel(const float* __restrict__ xyz) {
    #pragma clang fp contract(off)
    const int wave = blockIdx.x * 4 + (threadIdx.x >> 6);
    const int lane = threadIdx.x & 63;
    const int b = wave >> 9;
    const float* xb = xyz + b * 3 * NPTS;
    const int fi = g_fidx[wave] & (NPTS - 1);
    float ax = xb[fi];
    float ay = xb[NPTS + fi];
    float az = xb[2*NPTS + fi];
    float sa = ax*ax + ay*ay; sa = sa + az*az;
    float d[32];
    #pragma unroll
    for (int j = 0; j < 32; ++j) {
        int p = j * 64 + lane;
        float bx = xb[p];
        float by = xb[NPTS + p];
        float bz = xb[2*NPTS + p];
        float sb = bx*bx + by*by; sb = sb + bz*bz;
        float dot = ax*bx + ay*by; dot = dot + az*bz;
        float t1 = sa + sb;
        float t2 = 2.0f * dot;
        d[j] = t1 - t2;
    }
    for (int r = 0; r < KNB; ++r) {
        float best = 1e30f; int bi = 0x7fffffff;
        #pragma unroll
        for (int j = 0; j < 32; ++j) {
            if (d[j] < best) { best = d[j]; bi = j * 64 + lane; }
        }
        #pragma unroll
        for (int m = 32; m >= 1; m >>= 1) {
            float ov = __shfl_xor(best, m);
            int   oi = __shfl_xor(bi, m);
            if (ov < best || (ov == best && oi < bi)) { best = ov; bi = oi; }
        }
        bi &= (NPTS - 1);
        if (lane == 0) g_knn[wave * KNB + r] = bi;
        int rl = bi & 63, rs = bi >> 6;
        if (lane == rl) {
            #pragma unroll
            for (int j = 0; j < 32; ++j) if (j == rs) d[j] = 1e30f;
        }
    }
}

// ---------------------------------------------------------------------------
// score3_kernel: blocks 0-255 compute geometry ONCE and all THREE scoring
// MLPs; blocks 256-271 do the small gathered outputs.
// ---------------------------------------------------------------------------
__global__ __launch_bounds__(256) void score3_kernel(
    const float* __restrict__ xyz, const float* __restrict__ nrm,
    const float* __restrict__ Xa, const float* __restrict__ Ya,
    const float* __restrict__ w1_0, const float* __restrict__ b1_0,
    const float* __restrict__ w2_0, const float* __restrict__ b2_0,
    const float* __restrict__ w1_1, const float* __restrict__ b1_1,
    const float* __restrict__ w2_1, const float* __restrict__ b2_1,
    const float* __restrict__ w1_2, const float* __restrict__ b1_2,
    const float* __restrict__ w2_2, const float* __restrict__ b2_2,
    float* __restrict__ out) {
    const int bid = blockIdx.x;
    const int t = threadIdx.x;
    if (bid >= 256) {
        const int g = (bid - 256) * 256 + t;       // b*512+p
        const int b = g / NPOINT, p = g % NPOINT;
        const int fi = g_fidx[g] & (NPTS - 1);
        const int n0 = g_knn[g * KNB] & (NPTS - 1);
        #pragma unroll
        for (int a = 0; a < 3; ++a) {
            out[            (b*3 + a) * NPOINT + p] = xyz[(b*3 + a) * NPTS + fi];
            out[12288 +     (b*3 + a) * NPOINT + p] = nrm[(b*3 + a) * NPTS + n0];
            out[24576 +     (b*3 + a) * NPOINT + p] = Xa [(b*3 + a) * NPTS + n0];
            out[36864 +     (b*3 + a) * NPOINT + p] = Ya [(b*3 + a) * NPTS + n0];
        }
        return;
    }
    __shared__ float w1s[3][16][10];
    __shared__ float b1s[3][16];
    __shared__ float w2s[3][8][16];
    __shared__ float b2s[3][8];
    {
        const float* w1p[3] = {w1_0, w1_1, w1_2};
        const float* b1p[3] = {b1_0, b1_1, b1_2};
        const float* w2p[3] = {w2_0, w2_1, w2_2};
        const float* b2p[3] = {b2_0, b2_1, b2_2};
        #pragma unroll
        for (int l = 0; l < 3; ++l) {
            if (t < 160) w1s[l][t / 10][t % 10] = w1p[l][t];
            if (t < 16)  b1s[l][t] = b1p[l][t];
            if (t < 128) w2s[l][t / 16][t % 16] = w2p[l][t];
            if (t < 8)   b2s[l][t] = b2p[l][t];
        }
    }
    __syncthreads();
    const int row = bid * 256 + t;
    const int b = row >> 13;
    const int p = (row >> 4) & 511;
    const int n = g_knn[row] & (NPTS - 1);
    const int fi = g_fidx[b * NPOINT + p] & (NPTS - 1);
    const float* xb = xyz + b * 3 * NPTS;
    const float* nb = nrm + b * 3 * NPTS;
    const float* Xb = Xa  + b * 3 * NPTS;
    const float* Yb = Ya  + b * 3 * NPTS;
    float gx, gy, gz, sq, draw, nnv;
    {
        #pragma clang fp contract(off)
        gx = xb[n]        - xb[fi];
        gy = xb[NPTS + n] - xb[NPTS + fi];
        gz = xb[2*NPTS+n] - xb[2*NPTS+fi];
        sq = gx*gx + gy*gy;
        sq = sq + gz*gz;
        draw = sqrtf(sq + 1e-10f);
        nnv = sqrtf(sq);
    }
    float dmin = draw, dmax = draw;
    #pragma unroll
    for (int m = 1; m < 16; m <<= 1) {
        dmin = fminf(dmin, __shfl_xor(dmin, m, 16));
        dmax = fmaxf(dmax, __shfl_xor(dmax, m, 16));
    }
    float dist;
    {
        #pragma clang fp contract(off)
        dist = (draw - dmin) / ((dmax - dmin) + 1e-10f);
    }
    float nx = nb[n], ny = nb[NPTS+n], nz = nb[2*NPTS+n];
    float Xx = Xb[n], Xy = Xb[NPTS+n], Xz = Xb[2*NPTS+n];
    float Yx = Yb[n], Yy = Yb[NPTS+n], Yz = Yb[2*NPTS+n];
    float g[10];
    g[0]=gx; g[1]=gy; g[2]=gz; g[3]=dist; g[4]=nx; g[5]=ny; g[6]=nz;
    {
        float vs[3][3] = {{nx,ny,nz},{Xx,Xy,Xz},{Yx,Yy,Yz}};
        #pragma unroll
        for (int a = 0; a < 3; ++a) {
            float vx=vs[a][0], vy=vs[a][1], vz=vs[a][2];
            float dot, nv;
            {
                #pragma clang fp contract(off)
                dot = gx*vx + gy*vy; dot = dot + gz*vz;
                float s2 = vx*vx + vy*vy; s2 = s2 + vz*vz;
                nv = sqrtf(s2);
            }
            float cc = dot / (nnv * nv + 1e-8f);
            cc = fminf(1.0f, fmaxf(-1.0f, cc));
            g[7+a] = acosf(cc) / 3.14159274101257324f;
        }
    }
    #pragma unroll
    for (int l = 0; l < 3; ++l) {
        float h[16];
        #pragma unroll
        for (int i = 0; i < 16; ++i) {
            float a = b1s[l][i];
            #pragma unroll
            for (int j = 0; j < 10; ++j) a += w1s[l][i][j] * g[j];
            h[i] = fmaxf(a, 0.0f);
        }
        float e[8]; float mx = -1e30f;
        #pragma unroll
        for (int m = 0; m < 8; ++m) {
            float a = b2s[l][m];
            #pragma unroll
            for (int j = 0; j < 16; ++j) a += w2s[l][m][j] * h[j];
            e[m] = a; mx = fmaxf(mx, a);
        }
        float sum = 0.0f;
        #pragma unroll
        for (int m = 0; m < 8; ++m) { e[m] = expf(e[m] - mx); sum += e[m]; }
        #pragma unroll
        for (int m = 0; m < 8; ++m)
            g_S[(size_t)l * NROWS * 8 + (size_t)row * 8 + m] = e[m] / sum;
    }
}

// ---------------------------------------------------------------------------
// MFMA PAConv GEMM v3:
//  - B fragments loaded DIRECTLY from pre-converted bf16 bankT[n][k] (global,
//    L2-resident, identical lines across blocks) — no Bs LDS, no per-step
//    f32->bf16 conversion of the bank.
//  - As double-buffered on K-step parity -> ONE barrier per K-step.
//  - c0 outer / m inner: A row loaded+BN'd once per c-chunk (regs).
//  - LAYER>=1 staging applies previous BN+relu; LAYER<2 epilogue accumulates
//    per-channel sum/sumsq into g_sums.
// ---------------------------------------------------------------------------
template<int LAYER, int CIN, int COUT>
__global__ __launch_bounds__(256) void gemm_kernel(const float* __restrict__ gamma,
                                                   const float* __restrict__ beta,
                                                   float* __restrict__ dout) {
    const float* __restrict__ A = (LAYER == 0) ? g_pT : (LAYER == 1) ? g_act1 : g_act2;
    float* __restrict__ O = (LAYER == 0) ? g_act1 : (LAYER == 1) ? g_act2 : dout;
    constexpr int NT = COUT / 16;
    constexpr int KDIM = 8 * CIN;
    constexpr int BOFF = (LAYER == 0) ? B0_OFF : (LAYER == 1) ? B1_OFF : B2_OFF;
    __shared__ ushort_t As[2][64][36];
    __shared__ float s_scale[(LAYER >= 1) ? CIN : 1];
    __shared__ float s_shift[(LAYER >= 1) ? CIN : 1];
    __shared__ float s_red[(LAYER < 2) ? 2 : 1][(LAYER < 2) ? 4 : 1][(LAYER < 2) ? COUT : 1];

    const int t = threadIdx.x;
    const int lane = t & 63, w = t >> 6;
    const int q = lane >> 4, nlo = lane & 15;
    const int row0 = blockIdx.x * 64;
    const int arow_i = t >> 2, acg = t & 3;

    if constexpr (LAYER >= 1) {
        const float* sb = (LAYER == 1) ? g_sums : (g_sums + 256);
        if (t < CIN) {
            float mu  = sb[t] * (1.0f / 65536.0f);
            float var = sb[CIN + t] * (1.0f / 65536.0f) - mu * mu;
            var = fmaxf(var, 0.0f);
            float sc = gamma[t] / sqrtf(var + 1e-5f);
            s_scale[t] = sc;
            s_shift[t] = beta[t] - mu * sc;
        }
        __syncthreads();
    }

    size_t arow;
    if (LAYER == 0) {
        const int row = row0 + arow_i;
        const int b = row >> 13;
        const int n = g_knn[row] & (NPTS - 1);
        arow = (size_t)(b * NPTS + n) * 64;
    } else {
        arow = (size_t)(row0 + arow_i) * CIN;
    }
    const float* Sbase = g_S + (size_t)LAYER * NROWS * 8 + (size_t)(row0 + arow_i) * 8;

    float svv[8];
    #pragma unroll
    for (int m = 0; m < 8; ++m) svv[m] = Sbase[m];

    f32x4 acc[NT];
    #pragma unroll
    for (int i = 0; i < NT; ++i) acc[i] = (f32x4){0.f, 0.f, 0.f, 0.f};

    // per-wave B base: row nt*16+nlo, col q*8 within the k-chunk
    const ushort_t* btBase = g_bankT + BOFF + (size_t)nlo * KDIM + q * 8;

    int par = 0;
    for (int c0 = 0; c0 < CIN; c0 += 32) {
        // ---- load F chunk once, BN+relu once ----
        float v[8];
        {
            const float* ap = A + arow + c0 + acg * 8;
            float4 fa = *reinterpret_cast<const float4*>(ap);
            float4 fb = *reinterpret_cast<const float4*>(ap + 4);
            v[0]=fa.x; v[1]=fa.y; v[2]=fa.z; v[3]=fa.w;
            v[4]=fb.x; v[5]=fb.y; v[6]=fb.z; v[7]=fb.w;
            if constexpr (LAYER >= 1) {
                const int c = c0 + acg * 8;
                #pragma unroll
                for (int j = 0; j < 8; ++j)
                    v[j] = fmaxf(v[j] * s_scale[c + j] + s_shift[c + j], 0.f);
            }
        }
        for (int m = 0; m < 8; ++m) {
            // ---- stage A (sv[m]*F -> bf16) into parity buffer ----
            {
                const float sv = svv[m];
                uint_t* dst = reinterpret_cast<uint_t*>(&As[par][arow_i][acg * 8]);
                #pragma unroll
                for (int j = 0; j < 8; j += 2)
                    dst[j >> 1] = (uint_t)f2bf(sv * v[j]) | ((uint_t)f2bf(sv * v[j+1]) << 16);
            }
            __syncthreads();
            // ---- MFMA: A from LDS, B direct from global bankT ----
            union FragU { uint2 u2[2]; short8 s; } af;
            af.u2[0] = *reinterpret_cast<const uint2*>(&As[par][w*16 + nlo][q*8]);
            af.u2[1] = *reinterpret_cast<const uint2*>(&As[par][w*16 + nlo][q*8 + 4]);
            const ushort_t* bk = btBase + (m * CIN + c0);
            #pragma unroll
            for (int nt = 0; nt < NT; ++nt) {
                FragU bf;
                bf.u2[0] = *reinterpret_cast<const uint2*>(bk + (size_t)nt * 16 * KDIM);
                bf.u2[1] = *reinterpret_cast<const uint2*>(bk + (size_t)nt * 16 * KDIM + 4);
                acc[nt] = __builtin_amdgcn_mfma_f32_16x16x32_bf16(af.s, bf.s, acc[nt], 0, 0, 0);
            }
            par ^= 1;
        }
    }

    if constexpr (LAYER == 2) {
        // wave w holds rows w*16..w*16+15 = all K=16 neighbors of one (b,p)
        const int bp = (row0 >> 4) + w;
        const int b = bp >> 9, p = bp & 511;
        #pragma unroll
        for (int nt = 0; nt < NT; ++nt) {
            float mv = fmaxf(fmaxf(acc[nt][0], acc[nt][1]), fmaxf(acc[nt][2], acc[nt][3]));
            mv = fmaxf(mv, __shfl_xor(mv, 16));
            mv = fmaxf(mv, __shfl_xor(mv, 32));
            if (lane < 16)
                O[(size_t)(b * 256 + nt*16 + nlo) * NPOINT + p] = mv;
        }
    } else {
        // raw output + fused per-channel sum/sumsq
        #pragma unroll
        for (int nt = 0; nt < NT; ++nt)
            #pragma unroll
            for (int r2 = 0; r2 < 4; ++r2)
                O[(size_t)(row0 + w*16 + q*4 + r2) * COUT + nt*16 + nlo] = acc[nt][r2];
        #pragma unroll
        for (int nt = 0; nt < NT; ++nt) {
            float s  = acc[nt][0] + acc[nt][1] + acc[nt][2] + acc[nt][3];
            float ss = acc[nt][0]*acc[nt][0] + acc[nt][1]*acc[nt][1]
                     + acc[nt][2]*acc[nt][2] + acc[nt][3]*acc[nt][3];
            s  += __shfl_xor(s, 16);  s  += __shfl_xor(s, 32);
            ss += __shfl_xor(ss, 16); ss += __shfl_xor(ss, 32);
            if (q == 0) {
                s_red[0][w][nt*16 + nlo] = s;
                s_red[1][w][nt*16 + nlo] = ss;
            }
        }
        __syncthreads();
        if (t < COUT) {
            float s  = s_red[0][0][t] + s_red[0][1][t] + s_red[0][2][t] + s_red[0][3][t];
            float ss = s_red[1][0][t] + s_red[1][1][t] + s_red[1][2][t] + s_red[1][3][t];
            float* sb = (LAYER == 0) ? g_sums : (g_sums + 256);
            atomicAdd(&sb[t], s);
            atomicAdd(&sb[COUT + t], ss);
        }
    }
}

// ---------------------------------------------------------------------------
extern "C" void kernel_launch(void* const* d_in, const int* in_sizes, int n_in,
                              void* d_out, int out_size, void* d_ws, size_t ws_size,
                              hipStream_t stream) {
    const float* xyz    = (const float*)d_in[0];
    const float* nrm    = (const float*)d_in[1];
    const float* Xa     = (const float*)d_in[2];
    const float* Ya     = (const float*)d_in[3];
    const float* points = (const float*)d_in[4];
    const float* w1_0 = (const float*)d_in[5];  const float* b1_0 = (const float*)d_in[6];
    const float* w2_0 = (const float*)d_in[7];  const float* b2_0 = (const float*)d_in[8];
    const float* bank0 = (const float*)d_in[9];
    const float* g0 = (const float*)d_in[10];   const float* be0 = (const float*)d_in[11];
    const float* w1_1 = (const float*)d_in[12]; const float* b1_1 = (const float*)d_in[13];
    const float* w2_1 = (const float*)d_in[14]; const float* b2_1 = (const float*)d_in[15];
    const float* bank1 = (const float*)d_in[16];
    const float* g1 = (const float*)d_in[17];   const float* be1 = (const float*)d_in[18];
    const float* w1_2 = (const float*)d_in[19]; const float* b1_2 = (const float*)d_in[20];
    const float* w2_2 = (const float*)d_in[21]; const float* b2_2 = (const float*)d_in[22];
    const float* bank2 = (const float*)d_in[23];
    float* out = (float*)d_out;
    (void)d_ws; (void)ws_size; (void)in_sizes; (void)n_in; (void)out_size;

    // fps (0-7) + transpose (8-263) + zero sums (264) + bank conv (265-1672)
    front_kernel<<<1673, 256, 0, stream>>>(xyz, points, bank0, bank1, bank2);
    knn_kernel<<<1024, 256, 0, stream>>>(xyz);
    // geometry + all 3 score MLPs (0-255) + small outputs (256-271)
    score3_kernel<<<272, 256, 0, stream>>>(xyz, nrm, Xa, Ya,
                                           w1_0, b1_0, w2_0, b2_0,
                                           w1_1, b1_1, w2_1, b2_1,
                                           w1_2, b1_2, w2_2, b2_2, out);
    // layer 0: gather+GEMM -> raw act1 + BN stats
    gemm_kernel<0, 64, 64><<<1024, 256, 0, stream>>>(nullptr, nullptr, nullptr);
    // layer 1: BN0+relu fused in staging -> raw act2 + BN stats
    gemm_kernel<1, 64, 128><<<1024, 256, 0, stream>>>(g0, be0, nullptr);
    // layer 2: BN1+relu fused in staging -> fused max-k + transpose to d_out
    gemm_kernel<2, 128, 256><<<1024, 256, 0, stream>>>(g1, be1, out + 49152);
}

// Round 12
// 648.768 us; speedup vs baseline: 1.1898x; 1.1898x over previous
//
#include <hip/hip_runtime.h>
#include <math.h>

#define NBATCH 8
#define NPTS   2048
#define NPOINT 512
#define KNB    16
#define NROWS  (NBATCH*NPOINT*KNB)   // 65536

typedef unsigned short ushort_t;
typedef unsigned int   uint_t;
typedef unsigned long long ull_t;
typedef __attribute__((ext_vector_type(8))) short  short8;   // 8 bf16 (4 VGPRs)
typedef __attribute__((ext_vector_type(4))) float  f32x4;    // MFMA C/D

// g_bankF element offsets (bf16, MFMA-fragment-major: [kc][nt][lane][8])
#define B0_OFF 0        // COUT=64,  K=512  -> 32768 elems
#define B1_OFF 32768    // COUT=128, K=512  -> 65536
#define B2_OFF 98304    // COUT=256, K=1024 -> 262144
#define BT_TOT 360448

// ---------------------------------------------------------------------------
// Scratch in static __device__ globals. Referenced ONLY in device code.
// ---------------------------------------------------------------------------
__device__ __align__(16) int      g_fidx[NBATCH * NPOINT];        //  16 KB
__device__ __align__(16) int      g_knn [NROWS];                  // 256 KB
__device__ __align__(16) float    g_sums[1024];                   //   4 KB
__device__ __align__(16) float    g_pT  [NBATCH * NPTS * 64];     //   4 MB
__device__ __align__(16) float    g_S   [(size_t)3 * NROWS * 8];  //   6 MB
__device__ __align__(16) float    g_act1[(size_t)NROWS * 64];     //  16 MB
__device__ __align__(16) float    g_act2[(size_t)NROWS * 128];    //  32 MB
__device__ __align__(16) ushort_t g_bankF[BT_TOT];                // 704 KB bf16 fragments

// f32 -> bf16 round-to-nearest-even (finite inputs).
__device__ __forceinline__ ushort_t f2bf(float f) {
    uint_t u = __float_as_uint(f);
    return (ushort_t)((u + 0x7FFFu + ((u >> 16) & 1u)) >> 16);
}

// DPP-shifted copy of a u64 key (bound_ctrl=1: invalid lanes read 0, the
// identity for unsigned max of our non-negative keys).
template<int CTRL>
__device__ __forceinline__ ull_t dpp_u64(ull_t k) {
    int lo = (int)(uint_t)k;
    int hi = (int)(uint_t)(k >> 32);
    int slo = __builtin_amdgcn_update_dpp(0, lo, CTRL, 0xF, 0xF, true);
    int shi = __builtin_amdgcn_update_dpp(0, hi, CTRL, 0xF, 0xF, true);
    return ((ull_t)(uint_t)shi << 32) | (uint_t)slo;
}

// Convert one bank element into fragment-major bf16 layout.
// e enumerates (kc, nt, lane, j); value = bank[k=kc*32+q*8+j][n=nt*16+nlo].
template<int COUT>
__device__ __forceinline__ void bank_frag(const float* __restrict__ bank,
                                          ushort_t* __restrict__ dst, int e) {
    const int j = e & 7;
    const int lane = (e >> 3) & 63;
    const int rem = e >> 9;
    constexpr int NTL = COUT / 16;
    const int nt = rem % NTL;
    const int kc = rem / NTL;
    const int q = lane >> 4, nlo = lane & 15;
    const int k = kc * 32 + q * 8 + j;
    const int n = nt * 16 + nlo;
    dst[e] = f2bf(bank[(size_t)k * COUT + n]);
}

// ---------------------------------------------------------------------------
// front_kernel: blocks 0-7 = FPS; 8-263 = transpose points; 264 = zero sums;
// 265-1672 = convert banks to bf16 fragment-major layout (hidden under FPS).
// FPS: DPP wave argmax (row_shr 1/2/4/8 + row_bcast 15/31 -> lane 63),
// packed key (f32bits(dist)<<32)|~idx, parity-buffered s_key, 1 barrier/iter.
// ---------------------------------------------------------------------------
__global__ __launch_bounds__(256) void front_kernel(const float* __restrict__ xyz,
                                                    const float* __restrict__ points,
                                                    const float* __restrict__ bank0,
                                                    const float* __restrict__ bank1,
                                                    const float* __restrict__ bank2) {
    __shared__ float smem[3 * NPTS + 16];
    const int bid = blockIdx.x;
    const int t = threadIdx.x;

    if (bid >= NBATCH) {
        if (bid < NBATCH + 256) {
            // ---- transpose points ----
            float (*tile)[65] = reinterpret_cast<float(*)[65]>(smem);
            const int blk = bid - NBATCH;
            const int b = blk >> 5;
            const int n0 = (blk & 31) * 64;
            const int lane = t & 63, q = t >> 6;
            #pragma unroll
            for (int i = 0; i < 16; ++i) {
                int c = q * 16 + i;
                tile[c][lane] = points[(b * 64 + c) * NPTS + n0 + lane];
            }
            __syncthreads();
            #pragma unroll
            for (int i = 0; i < 16; ++i) {
                int n = q * 16 + i;
                g_pT[(size_t)(b * NPTS + n0 + n) * 64 + lane] = tile[lane][n];
            }
        } else if (bid == NBATCH + 256) {
            // ---- zero BN-stats ----
            #pragma unroll
            for (int j = 0; j < 4; ++j) g_sums[j * 256 + t] = 0.0f;
        } else {
            // ---- bank -> fragment-major bf16 ----
            const int e = (bid - (NBATCH + 257)) * 256 + t;
            if (e < 32768) {
                bank_frag<64>(bank0, g_bankF + B0_OFF, e);
            } else if (e < 98304) {
                bank_frag<128>(bank1, g_bankF + B1_OFF, e - 32768);
            } else {
                bank_frag<256>(bank2, g_bankF + B2_OFF, e - 98304);
            }
        }
        return;
    }

    // ---- FPS ----
    {
        #pragma clang fp contract(off)
        const int b = bid;
        const int lane = t & 63, w4 = t >> 6;
        const float* xb = xyz + b * 3 * NPTS;
        float* s_x = smem;
        float* s_y = smem + NPTS;
        float* s_z = smem + 2 * NPTS;
        ull_t* s_key = reinterpret_cast<ull_t*>(smem + 3 * NPTS);  // 8 slots
        float x[8], y[8], z[8], d[8];
        #pragma unroll
        for (int j = 0; j < 8; ++j) {
            int p = j * 256 + t;
            float vx = xb[p], vy = xb[NPTS + p], vz = xb[2*NPTS + p];
            x[j] = vx; y[j] = vy; z[j] = vz;
            s_x[p] = vx; s_y[p] = vy; s_z[p] = vz;
            d[j] = 1e10f;
        }
        __syncthreads();
        int far = 0;
        for (int i = 0; i < NPOINT; ++i) {
            if (t == 0) g_fidx[b * NPOINT + i] = far;
            float cx = s_x[far], cy = s_y[far], cz = s_z[far];
            float best = -1.0f; int bi = 0;
            #pragma unroll
            for (int j = 0; j < 8; ++j) {
                float dx = x[j] - cx;
                float dy = y[j] - cy;
                float dz = z[j] - cz;
                float dd = dx*dx + dy*dy;   // ((dx^2+dy^2)+dz^2) like np
                dd = dd + dz*dz;
                float dn = fminf(d[j], dd);
                d[j] = dn;
                if (dn > best) { best = dn; bi = j * 256 + t; }  // strict >
            }
            ull_t key = (((ull_t)__float_as_uint(best)) << 32) | (uint_t)(~bi);
            { ull_t s = dpp_u64<0x111>(key); if (s > key) key = s; }  // row_shr:1
            { ull_t s = dpp_u64<0x112>(key); if (s > key) key = s; }  // row_shr:2
            { ull_t s = dpp_u64<0x114>(key); if (s > key) key = s; }  // row_shr:4
            { ull_t s = dpp_u64<0x118>(key); if (s > key) key = s; }  // row_shr:8
            { ull_t s = dpp_u64<0x142>(key); if (s > key) key = s; }  // row_bcast:15
            { ull_t s = dpp_u64<0x143>(key); if (s > key) key = s; }  // row_bcast:31
            uint_t wlo = (uint_t)__builtin_amdgcn_readlane((int)(uint_t)key, 63);
            uint_t whi = (uint_t)__builtin_amdgcn_readlane((int)(uint_t)(key >> 32), 63);
            if (lane == 0) s_key[((i & 1) << 2) + w4] = ((ull_t)whi << 32) | wlo;
            __syncthreads();
            const ull_t* kb = s_key + ((i & 1) << 2);
            ull_t k0 = kb[0], k1 = kb[1], k2 = kb[2], k3 = kb[3];
            if (k1 > k0) k0 = k1;
            if (k3 > k2) k2 = k3;
            if (k2 > k0) k0 = k2;
            far = (int)(~(uint_t)k0) & (NPTS - 1);
        }
    }
}

// ---------------------------------------------------------------------------
// KNN: one wave per query. Expanded |a|^2+|b|^2-2ab form (contract off);
// 16 rounds of wave-min with index tie-break.
// ---------------------------------------------------------------------------
__global__ __launch_bounds__(256) void knn_kernel(const float* __restrict__ xyz) {
    #pragma clang fp contract(off)
    const int wave = blockIdx.x * 4 + (threadIdx.x >> 6);
    const int lane = threadIdx.x & 63;
    const int b = wave >> 9;
    const float* xb = xyz + b * 3 * NPTS;
    const int fi = g_fidx[wave] & (NPTS - 1);
    float ax = xb[fi];
    float ay = xb[NPTS + fi];
    float az = xb[2*NPTS + fi];
    float sa = ax*ax + ay*ay; sa = sa + az*az;
    float d[32];
    #pragma unroll
    for (int j = 0; j < 32; ++j) {
        int p = j * 64 + lane;
        float bx = xb[p];
        float by = xb[NPTS + p];
        float bz = xb[2*NPTS + p];
        float sb = bx*bx + by*by; sb = sb + bz*bz;
        float dot = ax*bx + ay*by; dot = dot + az*bz;
        float t1 = sa + sb;
        float t2 = 2.0f * dot;
        d[j] = t1 - t2;
    }
    for (int r = 0; r < KNB; ++r) {
        float best = 1e30f; int bi = 0x7fffffff;
        #pragma unroll
        for (int j = 0; j < 32; ++j) {
            if (d[j] < best) { best = d[j]; bi = j * 64 + lane; }
        }
        #pragma unroll
        for (int m = 32; m >= 1; m >>= 1) {
            float ov = __shfl_xor(best, m);
            int   oi = __shfl_xor(bi, m);
            if (ov < best || (ov == best && oi < bi)) { best = ov; bi = oi; }
        }
        bi &= (NPTS - 1);
        if (lane == 0) g_knn[wave * KNB + r] = bi;
        int rl = bi & 63, rs = bi >> 6;
        if (lane == rl) {
            #pragma unroll
            for (int j = 0; j < 32; ++j) if (j == rs) d[j] = 1e30f;
        }
    }
}

// ---------------------------------------------------------------------------
// score3_kernel: blocks 0-255 compute geometry ONCE and all THREE scoring
// MLPs; blocks 256-271 do the small gathered outputs.
// ---------------------------------------------------------------------------
__global__ __launch_bounds__(256) void score3_kernel(
    const float* __restrict__ xyz, const float* __restrict__ nrm,
    const float* __restrict__ Xa, const float* __restrict__ Ya,
    const float* __restrict__ w1_0, const float* __restrict__ b1_0,
    const float* __restrict__ w2_0, const float* __restrict__ b2_0,
    const float* __restrict__ w1_1, const float* __restrict__ b1_1,
    const float* __restrict__ w2_1, const float* __restrict__ b2_1,
    const float* __restrict__ w1_2, const float* __restrict__ b1_2,
    const float* __restrict__ w2_2, const float* __restrict__ b2_2,
    float* __restrict__ out) {
    const int bid = blockIdx.x;
    const int t = threadIdx.x;
    if (bid >= 256) {
        const int g = (bid - 256) * 256 + t;       // b*512+p
        const int b = g / NPOINT, p = g % NPOINT;
        const int fi = g_fidx[g] & (NPTS - 1);
        const int n0 = g_knn[g * KNB] & (NPTS - 1);
        #pragma unroll
        for (int a = 0; a < 3; ++a) {
            out[            (b*3 + a) * NPOINT + p] = xyz[(b*3 + a) * NPTS + fi];
            out[12288 +     (b*3 + a) * NPOINT + p] = nrm[(b*3 + a) * NPTS + n0];
            out[24576 +     (b*3 + a) * NPOINT + p] = Xa [(b*3 + a) * NPTS + n0];
            out[36864 +     (b*3 + a) * NPOINT + p] = Ya [(b*3 + a) * NPTS + n0];
        }
        return;
    }
    __shared__ float w1s[3][16][10];
    __shared__ float b1s[3][16];
    __shared__ float w2s[3][8][16];
    __shared__ float b2s[3][8];
    {
        const float* w1p[3] = {w1_0, w1_1, w1_2};
        const float* b1p[3] = {b1_0, b1_1, b1_2};
        const float* w2p[3] = {w2_0, w2_1, w2_2};
        const float* b2p[3] = {b2_0, b2_1, b2_2};
        #pragma unroll
        for (int l = 0; l < 3; ++l) {
            if (t < 160) w1s[l][t / 10][t % 10] = w1p[l][t];
            if (t < 16)  b1s[l][t] = b1p[l][t];
            if (t < 128) w2s[l][t / 16][t % 16] = w2p[l][t];
            if (t < 8)   b2s[l][t] = b2p[l][t];
        }
    }
    __syncthreads();
    const int row = bid * 256 + t;
    const int b = row >> 13;
    const int p = (row >> 4) & 511;
    const int n = g_knn[row] & (NPTS - 1);
    const int fi = g_fidx[b * NPOINT + p] & (NPTS - 1);
    const float* xb = xyz + b * 3 * NPTS;
    const float* nb = nrm + b * 3 * NPTS;
    const float* Xb = Xa  + b * 3 * NPTS;
    const float* Yb = Ya  + b * 3 * NPTS;
    float gx, gy, gz, sq, draw, nnv;
    {
        #pragma clang fp contract(off)
        gx = xb[n]        - xb[fi];
        gy = xb[NPTS + n] - xb[NPTS + fi];
        gz = xb[2*NPTS+n] - xb[2*NPTS+fi];
        sq = gx*gx + gy*gy;
        sq = sq + gz*gz;
        draw = sqrtf(sq + 1e-10f);
        nnv = sqrtf(sq);
    }
    float dmin = draw, dmax = draw;
    #pragma unroll
    for (int m = 1; m < 16; m <<= 1) {
        dmin = fminf(dmin, __shfl_xor(dmin, m, 16));
        dmax = fmaxf(dmax, __shfl_xor(dmax, m, 16));
    }
    float dist;
    {
        #pragma clang fp contract(off)
        dist = (draw - dmin) / ((dmax - dmin) + 1e-10f);
    }
    float nx = nb[n], ny = nb[NPTS+n], nz = nb[2*NPTS+n];
    float Xx = Xb[n], Xy = Xb[NPTS+n], Xz = Xb[2*NPTS+n];
    float Yx = Yb[n], Yy = Yb[NPTS+n], Yz = Yb[2*NPTS+n];
    float g[10];
    g[0]=gx; g[1]=gy; g[2]=gz; g[3]=dist; g[4]=nx; g[5]=ny; g[6]=nz;
    {
        float vs[3][3] = {{nx,ny,nz},{Xx,Xy,Xz},{Yx,Yy,Yz}};
        #pragma unroll
        for (int a = 0; a < 3; ++a) {
            float vx=vs[a][0], vy=vs[a][1], vz=vs[a][2];
            float dot, nv;
            {
                #pragma clang fp contract(off)
                dot = gx*vx + gy*vy; dot = dot + gz*vz;
                float s2 = vx*vx + vy*vy; s2 = s2 + vz*vz;
                nv = sqrtf(s2);
            }
            float cc = dot / (nnv * nv + 1e-8f);
            cc = fminf(1.0f, fmaxf(-1.0f, cc));
            g[7+a] = acosf(cc) / 3.14159274101257324f;
        }
    }
    #pragma unroll
    for (int l = 0; l < 3; ++l) {
        float h[16];
        #pragma unroll
        for (int i = 0; i < 16; ++i) {
            float a = b1s[l][i];
            #pragma unroll
            for (int j = 0; j < 10; ++j) a += w1s[l][i][j] * g[j];
            h[i] = fmaxf(a, 0.0f);
        }
        float e[8]; float mx = -1e30f;
        #pragma unroll
        for (int m = 0; m < 8; ++m) {
            float a = b2s[l][m];
            #pragma unroll
            for (int j = 0; j < 16; ++j) a += w2s[l][m][j] * h[j];
            e[m] = a; mx = fmaxf(mx, a);
        }
        float sum = 0.0f;
        #pragma unroll
        for (int m = 0; m < 8; ++m) { e[m] = expf(e[m] - mx); sum += e[m]; }
        #pragma unroll
        for (int m = 0; m < 8; ++m)
            g_S[(size_t)l * NROWS * 8 + (size_t)row * 8 + m] = e[m] / sum;
    }
}

// ---------------------------------------------------------------------------
// MFMA PAConv GEMM v4:
//  - B fragments: ONE fully-coalesced 16B/lane load per fragment from the
//    fragment-major bf16 g_bankF (1 KB contiguous per wave, L1/L2-shared
//    across waves and blocks) — fixes r11's 16-way address divergence.
//  - As double-buffered on K-step parity -> ONE barrier per K-step.
//  - c0 outer / m inner: A row loaded+BN'd once per c-chunk (regs).
//  - LAYER>=1 staging applies previous BN+relu; LAYER<2 epilogue accumulates
//    per-channel sum/sumsq into g_sums.
// ---------------------------------------------------------------------------
template<int LAYER, int CIN, int COUT>
__global__ __launch_bounds__(256) void gemm_kernel(const float* __restrict__ gamma,
                                                   const float* __restrict__ beta,
                                                   float* __restrict__ dout) {
    const float* __restrict__ A = (LAYER == 0) ? g_pT : (LAYER == 1) ? g_act1 : g_act2;
    float* __restrict__ O = (LAYER == 0) ? g_act1 : (LAYER == 1) ? g_act2 : dout;
    constexpr int NT = COUT / 16;
    constexpr int BOFF = (LAYER == 0) ? B0_OFF : (LAYER == 1) ? B1_OFF : B2_OFF;
    __shared__ ushort_t As[2][64][36];
    __shared__ float s_scale[(LAYER >= 1) ? CIN : 1];
    __shared__ float s_shift[(LAYER >= 1) ? CIN : 1];
    __shared__ float s_red[(LAYER < 2) ? 2 : 1][(LAYER < 2) ? 4 : 1][(LAYER < 2) ? COUT : 1];

    const int t = threadIdx.x;
    const int lane = t & 63, w = t >> 6;
    const int q = lane >> 4, nlo = lane & 15;
    const int row0 = blockIdx.x * 64;
    const int arow_i = t >> 2, acg = t & 3;

    if constexpr (LAYER >= 1) {
        const float* sb = (LAYER == 1) ? g_sums : (g_sums + 256);
        if (t < CIN) {
            float mu  = sb[t] * (1.0f / 65536.0f);
            float var = sb[CIN + t] * (1.0f / 65536.0f) - mu * mu;
            var = fmaxf(var, 0.0f);
            float sc = gamma[t] / sqrtf(var + 1e-5f);
            s_scale[t] = sc;
            s_shift[t] = beta[t] - mu * sc;
        }
        __syncthreads();
    }

    size_t arow;
    if (LAYER == 0) {
        const int row = row0 + arow_i;
        const int b = row >> 13;
        const int n = g_knn[row] & (NPTS - 1);
        arow = (size_t)(b * NPTS + n) * 64;
    } else {
        arow = (size_t)(row0 + arow_i) * CIN;
    }
    const float* Sbase = g_S + (size_t)LAYER * NROWS * 8 + (size_t)(row0 + arow_i) * 8;

    float svv[8];
    #pragma unroll
    for (int m = 0; m < 8; ++m) svv[m] = Sbase[m];

    f32x4 acc[NT];
    #pragma unroll
    for (int i = 0; i < NT; ++i) acc[i] = (f32x4){0.f, 0.f, 0.f, 0.f};

    // fragment base for this lane: chunk kc, tile nt -> + (kc*NT + nt)*512
    const ushort_t* fbase = g_bankF + BOFF + lane * 8;

    int par = 0;
    for (int c0 = 0; c0 < CIN; c0 += 32) {
        // ---- load F chunk once, BN+relu once ----
        float v[8];
        {
            const float* ap = A + arow + c0 + acg * 8;
            float4 fa = *reinterpret_cast<const float4*>(ap);
            float4 fb = *reinterpret_cast<const float4*>(ap + 4);
            v[0]=fa.x; v[1]=fa.y; v[2]=fa.z; v[3]=fa.w;
            v[4]=fb.x; v[5]=fb.y; v[6]=fb.z; v[7]=fb.w;
            if constexpr (LAYER >= 1) {
                const int c = c0 + acg * 8;
                #pragma unroll
                for (int j = 0; j < 8; ++j)
                    v[j] = fmaxf(v[j] * s_scale[c + j] + s_shift[c + j], 0.f);
            }
        }
        for (int m = 0; m < 8; ++m) {
            // ---- stage A (sv[m]*F -> bf16) into parity buffer ----
            {
                const float sv = svv[m];
                uint_t* dst = reinterpret_cast<uint_t*>(&As[par][arow_i][acg * 8]);
                #pragma unroll
                for (int j = 0; j < 8; j += 2)
                    dst[j >> 1] = (uint_t)f2bf(sv * v[j]) | ((uint_t)f2bf(sv * v[j+1]) << 16);
            }
            __syncthreads();
            // ---- MFMA: A from LDS, B coalesced from g_bankF ----
            union FragU { uint2 u2[2]; short8 s; } af;
            af.u2[0] = *reinterpret_cast<const uint2*>(&As[par][w*16 + nlo][q*8]);
            af.u2[1] = *reinterpret_cast<const uint2*>(&As[par][w*16 + nlo][q*8 + 4]);
            const int kc = m * (CIN / 32) + (c0 >> 5);
            const ushort_t* bk = fbase + (size_t)(kc * NT) * 512;
            #pragma unroll
            for (int nt = 0; nt < NT; ++nt) {
                FragU bf;
                bf.u2[0] = *reinterpret_cast<const uint2*>(bk + (size_t)nt * 512);
                bf.u2[1] = *reinterpret_cast<const uint2*>(bk + (size_t)nt * 512 + 4);
                acc[nt] = __builtin_amdgcn_mfma_f32_16x16x32_bf16(af.s, bf.s, acc[nt], 0, 0, 0);
            }
            par ^= 1;
        }
    }

    if constexpr (LAYER == 2) {
        // wave w holds rows w*16..w*16+15 = all K=16 neighbors of one (b,p)
        const int bp = (row0 >> 4) + w;
        const int b = bp >> 9, p = bp & 511;
        #pragma unroll
        for (int nt = 0; nt < NT; ++nt) {
            float mv = fmaxf(fmaxf(acc[nt][0], acc[nt][1]), fmaxf(acc[nt][2], acc[nt][3]));
            mv = fmaxf(mv, __shfl_xor(mv, 16));
            mv = fmaxf(mv, __shfl_xor(mv, 32));
            if (lane < 16)
                O[(size_t)(b * 256 + nt*16 + nlo) * NPOINT + p] = mv;
        }
    } else {
        // raw output + fused per-channel sum/sumsq
        #pragma unroll
        for (int nt = 0; nt < NT; ++nt)
            #pragma unroll
            for (int r2 = 0; r2 < 4; ++r2)
                O[(size_t)(row0 + w*16 + q*4 + r2) * COUT + nt*16 + nlo] = acc[nt][r2];
        #pragma unroll
        for (int nt = 0; nt < NT; ++nt) {
            float s  = acc[nt][0] + acc[nt][1] + acc[nt][2] + acc[nt][3];
            float ss = acc[nt][0]*acc[nt][0] + acc[nt][1]*acc[nt][1]
                     + acc[nt][2]*acc[nt][2] + acc[nt][3]*acc[nt][3];
            s  += __shfl_xor(s, 16);  s  += __shfl_xor(s, 32);
            ss += __shfl_xor(ss, 16); ss += __shfl_xor(ss, 32);
            if (q == 0) {
                s_red[0][w][nt*16 + nlo] = s;
                s_red[1][w][nt*16 + nlo] = ss;
            }
        }
        __syncthreads();
        if (t < COUT) {
            float s  = s_red[0][0][t] + s_red[0][1][t] + s_red[0][2][t] + s_red[0][3][t];
            float ss = s_red[1][0][t] + s_red[1][1][t] + s_red[1][2][t] + s_red[1][3][t];
            float* sb = (LAYER == 0) ? g_sums : (g_sums + 256);
            atomicAdd(&sb[t], s);
            atomicAdd(&sb[COUT + t], ss);
        }
    }
}

// ---------------------------------------------------------------------------
extern "C" void kernel_launch(void* const* d_in, const int* in_sizes, int n_in,
                              void* d_out, int out_size, void* d_ws, size_t ws_size,
                              hipStream_t stream) {
    const float* xyz    = (const float*)d_in[0];
    const float* nrm    = (const float*)d_in[1];
    const float* Xa     = (const float*)d_in[2];
    const float* Ya     = (const float*)d_in[3];
    const float* points = (const float*)d_in[4];
    const float* w1_0 = (const float*)d_in[5];  const float* b1_0 = (const float*)d_in[6];
    const float* w2_0 = (const float*)d_in[7];  const float* b2_0 = (const float*)d_in[8];
    const float* bank0 = (const float*)d_in[9];
    const float* g0 = (const float*)d_in[10];   const float* be0 = (const float*)d_in[11];
    const float* w1_1 = (const float*)d_in[12]; const float* b1_1 = (const float*)d_in[13];
    const float* w2_1 = (const float*)d_in[14]; const float* b2_1 = (const float*)d_in[15];
    const float* bank1 = (const float*)d_in[16];
    const float* g1 = (const float*)d_in[17];   const float* be1 = (const float*)d_in[18];
    const float* w1_2 = (const float*)d_in[19]; const float* b1_2 = (const float*)d_in[20];
    const float* w2_2 = (const float*)d_in[21]; const float* b2_2 = (const float*)d_in[22];
    const float* bank2 = (const float*)d_in[23];
    float* out = (float*)d_out;
    (void)d_ws; (void)ws_size; (void)in_sizes; (void)n_in; (void)out_size;

    // fps (0-7) + transpose (8-263) + zero sums (264) + bank frag conv (265-1672)
    front_kernel<<<1673, 256, 0, stream>>>(xyz, points, bank0, bank1, bank2);
    knn_kernel<<<1024, 256, 0, stream>>>(xyz);
    // geometry + all 3 score MLPs (0-255) + small outputs (256-271)
    score3_kernel<<<272, 256, 0, stream>>>(xyz, nrm, Xa, Ya,
                                           w1_0, b1_0, w2_0, b2_0,
                                           w1_1, b1_1, w2_1, b2_1,
                                           w1_2, b1_2, w2_2, b2_2, out);
    // layer 0: gather+GEMM -> raw act1 + BN stats
    gemm_kernel<0, 64, 64><<<1024, 256, 0, stream>>>(nullptr, nullptr, nullptr);
    // layer 1: BN0+relu fused in staging -> raw act2 + BN stats
    gemm_kernel<1, 64, 128><<<1024, 256, 0, stream>>>(g0, be0, nullptr);
    // layer 2: BN1+relu fused in staging -> fused max-k + transpose to d_out
    gemm_kernel<2, 128, 256><<<1024, 256, 0, stream>>>(g1, be1, out + 49152);
}